// Round 1
// baseline (1797.559 us; speedup 1.0000x reference)
//
#include <hip/hip_runtime.h>
#include <math.h>

#define BATCH 1024
#define LABEL 128
#define LATENT 512
#define NTOT 1152  // 1024 + 128

// ---------------- conv1 (1->32, 5x5 SAME) + relu + 2x2 maxpool ----------------
// in [N,1,28,28] -> out [N,32,14,14]
__global__ __launch_bounds__(256) void conv1_pool(const float* __restrict__ in,
                                                  const float* __restrict__ wt,
                                                  const float* __restrict__ bias,
                                                  float* __restrict__ out) {
    const int n = blockIdx.x;
    __shared__ float pin[32][32];     // padded 28+2+2
    __shared__ float wts[32 * 25];
    const int tid = threadIdx.x;
    for (int idx = tid; idx < 32 * 32; idx += 256) ((float*)pin)[idx] = 0.f;
    __syncthreads();
    for (int idx = tid; idx < 784; idx += 256) {
        int y = idx / 28, x = idx % 28;
        pin[y + 2][x + 2] = in[n * 784 + idx];
    }
    for (int idx = tid; idx < 800; idx += 256) wts[idx] = wt[idx];
    __syncthreads();
    for (int o = tid; o < 32 * 196; o += 256) {
        int oc = o / 196, p = o % 196, py = p / 14, px = p % 14;
        float b = bias[oc];
        float m = -1e30f;
        #pragma unroll
        for (int dy = 0; dy < 2; ++dy)
        #pragma unroll
        for (int dx = 0; dx < 2; ++dx) {
            int cy = 2 * py + dy, cx = 2 * px + dx;
            float acc = b;
            #pragma unroll
            for (int ky = 0; ky < 5; ++ky)
            #pragma unroll
            for (int kx = 0; kx < 5; ++kx)
                acc += pin[cy + ky][cx + kx] * wts[oc * 25 + ky * 5 + kx];
            m = fmaxf(m, acc);
        }
        out[n * 6272 + o] = fmaxf(m, 0.f);
    }
}

// ---------------- conv2 (32->64, 5x5 SAME) + relu + 2x2 maxpool ----------------
// in [N,32,14,14] -> out [N,64,7,7] (flattened [N,3136])
__global__ __launch_bounds__(256) void conv2_pool(const float* __restrict__ in,
                                                  const float* __restrict__ wt,
                                                  const float* __restrict__ bias,
                                                  float* __restrict__ out) {
    const int n = blockIdx.x;
    __shared__ float pin[32][18][18];   // padded 14+2+2 per channel
    const int tid = threadIdx.x;
    for (int idx = tid; idx < 32 * 18 * 18; idx += 256) ((float*)pin)[idx] = 0.f;
    __syncthreads();
    for (int idx = tid; idx < 6272; idx += 256) {
        int ic = idx / 196, r = idx % 196, y = r / 14, x = r % 14;
        pin[ic][y + 2][x + 2] = in[n * 6272 + idx];
    }
    __syncthreads();
    for (int o = tid; o < 64 * 49; o += 256) {
        int oc = o / 49, p = o % 49, py = p / 7, px = p % 7;
        float b = bias[oc];
        float a00 = b, a01 = b, a10 = b, a11 = b;
        const float* wo = wt + oc * 800;
        for (int ic = 0; ic < 32; ++ic) {
            float win[6][6];
            #pragma unroll
            for (int wy = 0; wy < 6; ++wy)
            #pragma unroll
            for (int wx = 0; wx < 6; ++wx)
                win[wy][wx] = pin[ic][2 * py + wy][2 * px + wx];
            const float* wic = wo + ic * 25;
            #pragma unroll
            for (int ky = 0; ky < 5; ++ky)
            #pragma unroll
            for (int kx = 0; kx < 5; ++kx) {
                float wv = wic[ky * 5 + kx];
                a00 += win[ky + 0][kx + 0] * wv;
                a01 += win[ky + 0][kx + 1] * wv;
                a10 += win[ky + 1][kx + 0] * wv;
                a11 += win[ky + 1][kx + 1] * wv;
            }
        }
        float m = fmaxf(fmaxf(a00, a01), fmaxf(a10, a11));
        out[n * 3136 + o] = fmaxf(m, 0.f);
    }
}

// ---------------- fc1 GEMM: [1152,3136] @ [512,3136]^T + b ----------------
// rows < 1024 -> lat ; rows >= 1024 -> rep = tanh(...)
__global__ __launch_bounds__(256) void fc1_gemm(const float* __restrict__ A,
                                                const float* __restrict__ B,
                                                const float* __restrict__ bias,
                                                float* __restrict__ lat,
                                                float* __restrict__ rep) {
    __shared__ float As[16][68];
    __shared__ float Bs[16][68];
    const int tid = threadIdx.x;
    const int n0 = blockIdx.x * 64, m0 = blockIdx.y * 64;
    const int lr = tid >> 2;           // 0..63
    const int lk = (tid & 3) * 4;      // 0,4,8,12
    const int ty = tid >> 4, tx = tid & 15;
    float c[4][4] = {};
    for (int k0 = 0; k0 < 3136; k0 += 16) {
        float4 a4 = *(const float4*)(A + (size_t)(n0 + lr) * 3136 + k0 + lk);
        float4 b4 = *(const float4*)(B + (size_t)(m0 + lr) * 3136 + k0 + lk);
        __syncthreads();
        As[lk + 0][lr] = a4.x; As[lk + 1][lr] = a4.y; As[lk + 2][lr] = a4.z; As[lk + 3][lr] = a4.w;
        Bs[lk + 0][lr] = b4.x; Bs[lk + 1][lr] = b4.y; Bs[lk + 2][lr] = b4.z; Bs[lk + 3][lr] = b4.w;
        __syncthreads();
        #pragma unroll
        for (int kk = 0; kk < 16; ++kk) {
            float av[4], bv[4];
            #pragma unroll
            for (int i = 0; i < 4; ++i) av[i] = As[kk][ty * 4 + i];
            #pragma unroll
            for (int j = 0; j < 4; ++j) bv[j] = Bs[kk][tx * 4 + j];
            #pragma unroll
            for (int i = 0; i < 4; ++i)
            #pragma unroll
            for (int j = 0; j < 4; ++j) c[i][j] += av[i] * bv[j];
        }
    }
    #pragma unroll
    for (int i = 0; i < 4; ++i)
    #pragma unroll
    for (int j = 0; j < 4; ++j) {
        int n = n0 + ty * 4 + i, m = m0 + tx * 4 + j;
        float v = c[i][j] + bias[m];
        if (n < 1024) lat[n * 512 + m] = v;
        else rep[(n - 1024) * 512 + m] = tanhf(v);
    }
}

// ---------------- label = softmax(lat @ fcn_w.T + fcn_b) ----------------
__global__ __launch_bounds__(128) void fcn_softmax(const float* __restrict__ lat,
                                                   const float* __restrict__ fw,
                                                   const float* __restrict__ fb,
                                                   float* __restrict__ out) {
    const int b = blockIdx.x;
    const int j = threadIdx.x;   // 0..127
    __shared__ float lrow[512];
    __shared__ float red[128];
    for (int i = j; i < 512; i += 128) lrow[i] = lat[b * 512 + i];
    __syncthreads();
    const float4* w4 = (const float4*)(fw + j * 512);
    float acc = fb[j];
    #pragma unroll 4
    for (int q = 0; q < 128; ++q) {
        float4 a = ((const float4*)lrow)[q];
        float4 w = w4[q];
        acc += a.x * w.x + a.y * w.y + a.z * w.z + a.w * w.w;
    }
    red[j] = acc;
    __syncthreads();
    for (int off = 64; off >= 1; off >>= 1) {
        if (j < off) red[j] = fmaxf(red[j], red[j + off]);
        __syncthreads();
    }
    float mx = red[0];
    __syncthreads();
    float ex = expf(acc - mx);
    red[j] = ex;
    __syncthreads();
    for (int off = 64; off >= 1; off >>= 1) {
        if (j < off) red[j] += red[j + off];
        __syncthreads();
    }
    out[b * 128 + j] = ex / red[0];
}

// ---------------- rho = mean(rep) ----------------
__global__ __launch_bounds__(256) void rho_kernel(const float* __restrict__ rep,
                                                  float* __restrict__ rho) {
    __shared__ float red[256];
    const int tid = threadIdx.x;
    float s = 0.f;
    for (int i = tid; i < LABEL * LATENT; i += 256) s += rep[i];
    red[tid] = s;
    __syncthreads();
    for (int off = 128; off >= 1; off >>= 1) {
        if (tid < off) red[tid] += red[tid + off];
        __syncthreads();
    }
    if (tid == 0) rho[0] = red[0] / (float)(LABEL * LATENT);
}

// ---------------- tT[i][k] = rep[k][i] - rho ----------------
__global__ __launch_bounds__(256) void t_kernel(const float* __restrict__ rep,
                                                const float* __restrict__ rho,
                                                float* __restrict__ tT) {
    int idx = blockIdx.x * 256 + threadIdx.x;   // 65536 total
    int i = idx / 128, k = idx % 128;
    tT[idx] = rep[k * 512 + i] - rho[0];
}

// ---------------- w[i][j] = dot(tT_i, tT_j)/128, zero diag ----------------
__global__ __launch_bounds__(256) void w_kernel(const float* __restrict__ tT,
                                                float* __restrict__ w) {
    int idx = blockIdx.x * 256 + threadIdx.x;   // 262144 total
    int i = idx >> 9, j = idx & 511;
    const float4* a = (const float4*)(tT + i * 128);
    const float4* b = (const float4*)(tT + j * 128);
    float acc = 0.f;
    #pragma unroll 8
    for (int q = 0; q < 32; ++q) {
        float4 av = a[q], bv = b[q];
        acc += av.x * bv.x + av.y * bv.y + av.z * bv.z + av.w * bv.w;
    }
    w[idx] = (i == j) ? 0.f : acc * (1.f / 128.f);
}

// ---------------- clustering + fused out = softmax(|min_s @ rep.T|) ----------------
// One block handles CB batch rows. 256 threads; thread owns columns 2*tid, 2*tid+1.
// w is exactly symmetric, so the energy matvec of iter k is the update matvec of
// iter k+1 -> one matvec per iteration. Synchronous Hopfield with symmetric W
// has period <= 2 (Goles), so stopping when s_k == s_{k-1} (fixed point) or
// s_k == s_{k-2} (2-cycle) is exactly equivalent to running all 512 iterations.
#define CB 4
__device__ __forceinline__ float sgnf(float x) {
    return (x > 0.f) ? 1.f : ((x < 0.f) ? -1.f : 0.f);
}

__global__ __launch_bounds__(256) void clustering(const float* __restrict__ lat,
                                                  const float* __restrict__ w,
                                                  const float* __restrict__ rep,
                                                  float* __restrict__ out) {
    const int tid = threadIdx.x;
    const int row0 = blockIdx.x * CB;
    __shared__ float buf[3][CB][512];
    __shared__ float mins[CB][512];
    __shared__ float red[256];
    __shared__ float part_e[4][CB];
    __shared__ int part_f[4];
    __shared__ float min_e[CB];
    __shared__ int copyf[CB];
    __shared__ int donef[CB];
    const int i0 = 2 * tid, i1 = 2 * tid + 1;
    const int wave = tid >> 6, lane = tid & 63;

    #pragma unroll
    for (int r = 0; r < CB; ++r) {
        buf[0][r][i0] = tanhf(lat[(row0 + r) * 512 + i0]);
        buf[0][r][i1] = tanhf(lat[(row0 + r) * 512 + i1]);
    }
    if (tid < CB) { min_e[tid] = INFINITY; donef[tid] = 0; }
    __syncthreads();

    // h_0 = s_0 @ w
    float h0[CB], h1[CB];
    #pragma unroll
    for (int r = 0; r < CB; ++r) { h0[r] = 0.f; h1[r] = 0.f; }
    #pragma unroll 4
    for (int j = 0; j < 512; ++j) {
        float2 wv = *(const float2*)(w + (size_t)j * 512 + i0);
        #pragma unroll
        for (int r = 0; r < CB; ++r) {
            float sj = buf[0][r][j];
            h0[r] += sj * wv.x;
            h1[r] += sj * wv.y;
        }
    }

    for (int k = 1; k <= 512; ++k) {
        const int nw = k % 3, pv = (k + 2) % 3, pp = (k + 1) % 3;
        float sn0[CB], sn1[CB];
        int eqbits = 0xFF;
        #pragma unroll
        for (int r = 0; r < CB; ++r) {
            float p0 = buf[pv][r][i0], p1 = buf[pv][r][i1];
            float q0 = buf[pp][r][i0], q1 = buf[pp][r][i1];
            sn0[r] = fabsf(p0) * sgnf(h0[r]);
            sn1[r] = fabsf(p1) * sgnf(h1[r]);
            if (!(sn0[r] == p0 && sn1[r] == p1)) eqbits &= ~(1 << r);
            if (!(sn0[r] == q0 && sn1[r] == q1)) eqbits &= ~(1 << (4 + r));
            buf[nw][r][i0] = sn0[r];
            buf[nw][r][i1] = sn1[r];
        }
        __syncthreads();
        // h_k = s_k @ w   (doubles as energy matvec)
        #pragma unroll
        for (int r = 0; r < CB; ++r) { h0[r] = 0.f; h1[r] = 0.f; }
        #pragma unroll 4
        for (int j = 0; j < 512; ++j) {
            float2 wv = *(const float2*)(w + (size_t)j * 512 + i0);
            #pragma unroll
            for (int r = 0; r < CB; ++r) {
                float sj = buf[nw][r][j];
                h0[r] += sj * wv.x;
                h1[r] += sj * wv.y;
            }
        }
        float ep[CB];
        #pragma unroll
        for (int r = 0; r < CB; ++r) ep[r] = sn0[r] * h0[r] + sn1[r] * h1[r];
        // butterfly reduce within wave (sum e, and flags)
        #pragma unroll
        for (int m = 32; m >= 1; m >>= 1) {
            #pragma unroll
            for (int r = 0; r < CB; ++r) ep[r] += __shfl_xor(ep[r], m, 64);
            eqbits &= __shfl_xor(eqbits, m, 64);
        }
        if (lane == 0) {
            #pragma unroll
            for (int r = 0; r < CB; ++r) part_e[wave][r] = ep[r];
            part_f[wave] = eqbits;
        }
        __syncthreads();
        if (tid < CB) {
            int r = tid;
            float e = -(part_e[0][r] + part_e[1][r] + part_e[2][r] + part_e[3][r]);
            int fl = part_f[0] & part_f[1] & part_f[2] & part_f[3];
            int better = e < min_e[r];
            if (better) min_e[r] = e;
            copyf[r] = better;
            int fixedp = (fl >> r) & 1;
            int cyc = (k >= 2) && ((fl >> (4 + r)) & 1);
            if (fixedp || cyc) donef[r] = 1;
        }
        __syncthreads();
        int alldone = 1;
        #pragma unroll
        for (int r = 0; r < CB; ++r) {
            if (copyf[r]) { mins[r][i0] = sn0[r]; mins[r][i1] = sn1[r]; }
            alldone &= donef[r];
        }
        if (alldone) break;
    }
    __syncthreads();

    // out[row] = softmax_j(|sum_i mins[i] * rep[j][i]|)
    const int j = tid & 127, half = tid >> 7;
    for (int r = 0; r < CB; ++r) {
        const float4* rr = (const float4*)(rep + (size_t)j * 512 + half * 256);
        const float4* ms = (const float4*)(&mins[r][half * 256]);
        float p = 0.f;
        #pragma unroll 8
        for (int q = 0; q < 64; ++q) {
            float4 rv = rr[q], mv = ms[q];
            p += rv.x * mv.x + rv.y * mv.y + rv.z * mv.z + rv.w * mv.w;
        }
        red[tid] = p;
        __syncthreads();
        float v = 0.f;
        if (tid < 128) { v = fabsf(red[tid] + red[tid + 128]); red[tid] = v; }
        __syncthreads();
        for (int off = 64; off >= 1; off >>= 1) {
            if (tid < off) red[tid] = fmaxf(red[tid], red[tid + off]);
            __syncthreads();
        }
        float mx = red[0];
        __syncthreads();
        float ex = 0.f;
        if (tid < 128) { ex = expf(v - mx); red[tid] = ex; }
        __syncthreads();
        for (int off = 64; off >= 1; off >>= 1) {
            if (tid < off) red[tid] += red[tid + off];
            __syncthreads();
        }
        if (tid < 128) out[(size_t)(row0 + r) * 128 + tid] = ex / red[0];
        __syncthreads();
    }
}

extern "C" void kernel_launch(void* const* d_in, const int* in_sizes, int n_in,
                              void* d_out, int out_size, void* d_ws, size_t ws_size,
                              hipStream_t stream) {
    const float* image = (const float*)d_in[0];
    const float* limg  = (const float*)d_in[1];
    const float* c1w   = (const float*)d_in[2];
    const float* c1b   = (const float*)d_in[3];
    const float* c2w   = (const float*)d_in[4];
    const float* c2b   = (const float*)d_in[5];
    const float* f1w   = (const float*)d_in[6];
    const float* f1b   = (const float*)d_in[7];
    const float* fnw   = (const float*)d_in[8];
    const float* fnb   = (const float*)d_in[9];
    float* out = (float*)d_out;   // [1024*128 out][1024*128 label]
    float* ws  = (float*)d_ws;

    float* out1 = ws;                          // 1152*6272
    float* out2 = out1 + (size_t)NTOT * 6272;  // 1152*3136
    float* lat  = out2 + (size_t)NTOT * 3136;  // 1024*512
    float* rep  = lat + (size_t)BATCH * 512;   // 128*512
    float* tT   = rep + (size_t)LABEL * 512;   // 512*128
    float* wmat = tT + (size_t)512 * 128;      // 512*512
    float* rho  = wmat + (size_t)512 * 512;    // 1

    hipLaunchKernelGGL(conv1_pool, dim3(BATCH), dim3(256), 0, stream, image, c1w, c1b, out1);
    hipLaunchKernelGGL(conv1_pool, dim3(LABEL), dim3(256), 0, stream, limg, c1w, c1b,
                       out1 + (size_t)BATCH * 6272);
    hipLaunchKernelGGL(conv2_pool, dim3(NTOT), dim3(256), 0, stream, out1, c2w, c2b, out2);
    hipLaunchKernelGGL(fc1_gemm, dim3(NTOT / 64, 512 / 64), dim3(256), 0, stream,
                       out2, f1w, f1b, lat, rep);
    hipLaunchKernelGGL(fcn_softmax, dim3(BATCH), dim3(128), 0, stream, lat, fnw, fnb,
                       out + (size_t)BATCH * LABEL);
    hipLaunchKernelGGL(rho_kernel, dim3(1), dim3(256), 0, stream, rep, rho);
    hipLaunchKernelGGL(t_kernel, dim3(256), dim3(256), 0, stream, rep, rho, tT);
    hipLaunchKernelGGL(w_kernel, dim3(1024), dim3(256), 0, stream, tT, wmat);
    hipLaunchKernelGGL(clustering, dim3(BATCH / CB), dim3(256), 0, stream, lat, wmat, rep, out);
}

// Round 2
// 909.438 us; speedup vs baseline: 1.9766x; 1.9766x over previous
//
#include <hip/hip_runtime.h>
#include <math.h>

#define BATCH 1024
#define LABEL 128
#define LATENT 512
#define NTOT 1152  // 1024 + 128

// ---------------- conv1 (1->32, 5x5 SAME) + relu + 2x2 maxpool ----------------
// in [N,1,28,28] -> out [N,32,14,14]
__global__ __launch_bounds__(256) void conv1_pool(const float* __restrict__ in,
                                                  const float* __restrict__ wt,
                                                  const float* __restrict__ bias,
                                                  float* __restrict__ out) {
    const int n = blockIdx.x;
    __shared__ float pin[32][32];     // padded 28+2+2
    __shared__ float wts[32 * 25];
    const int tid = threadIdx.x;
    for (int idx = tid; idx < 32 * 32; idx += 256) ((float*)pin)[idx] = 0.f;
    __syncthreads();
    for (int idx = tid; idx < 784; idx += 256) {
        int y = idx / 28, x = idx % 28;
        pin[y + 2][x + 2] = in[n * 784 + idx];
    }
    for (int idx = tid; idx < 800; idx += 256) wts[idx] = wt[idx];
    __syncthreads();
    for (int o = tid; o < 32 * 196; o += 256) {
        int oc = o / 196, p = o % 196, py = p / 14, px = p % 14;
        float b = bias[oc];
        float m = -1e30f;
        #pragma unroll
        for (int dy = 0; dy < 2; ++dy)
        #pragma unroll
        for (int dx = 0; dx < 2; ++dx) {
            int cy = 2 * py + dy, cx = 2 * px + dx;
            float acc = b;
            #pragma unroll
            for (int ky = 0; ky < 5; ++ky)
            #pragma unroll
            for (int kx = 0; kx < 5; ++kx)
                acc += pin[cy + ky][cx + kx] * wts[oc * 25 + ky * 5 + kx];
            m = fmaxf(m, acc);
        }
        out[n * 6272 + o] = fmaxf(m, 0.f);
    }
}

// ---------------- weight re-layout for conv2: w2[ic][oc][28] ----------------
__global__ __launch_bounds__(256) void w2prep(const float* __restrict__ w,
                                              float* __restrict__ w2) {
    int idx = blockIdx.x * 256 + threadIdx.x;   // 32*64*28 = 57344
    if (idx >= 32 * 64 * 28) return;
    int k = idx % 28, t = idx / 28;
    int oc = t % 64, ic = t / 64;
    w2[idx] = (k < 25) ? w[oc * 800 + ic * 25 + k] : 0.f;
}

// ---------------- conv2 (32->64, 5x5 SAME) + relu + 2x2 maxpool ----------------
// Broadcast layout: lane = oc (64), wave = pool quadrant (dy,dx).
// Each thread accumulates all 49 pooled positions for its (oc, quadrant) in regs.
// Input rows read via ds_read_b128 broadcasts (conflict-free); weights via
// aligned float4 global loads from pre-transposed w2 (L2-resident).
template<int DX>
__device__ __forceinline__ void conv_ic(const float* __restrict__ prow,
                                        const float* __restrict__ wk,
                                        float* __restrict__ acc) {
    #pragma unroll
    for (int yp = 0; yp < 17; ++yp) {
        float row[20];
        const float4* rp = (const float4*)(prow + yp * 20);
        #pragma unroll
        for (int v = 0; v < 5; ++v) {
            float4 t = rp[v];
            row[4 * v + 0] = t.x; row[4 * v + 1] = t.y;
            row[4 * v + 2] = t.z; row[4 * v + 3] = t.w;
        }
        #pragma unroll
        for (int ky = 0; ky < 5; ++ky) {
            const int rem = yp - ky;            // = 2*py; compile-time after unroll
            if (rem < 0 || rem > 12 || (rem & 1)) continue;
            const int py = rem >> 1;
            #pragma unroll
            for (int kx = 0; kx < 5; ++kx) {
                float w = wk[ky * 5 + kx];
                #pragma unroll
                for (int px = 0; px < 7; ++px)
                    acc[py * 7 + px] = fmaf(row[2 * px + DX + kx], w, acc[py * 7 + px]);
            }
        }
    }
}

__global__ __launch_bounds__(256) void conv2_pool(const float* __restrict__ in,
                                                  const float* __restrict__ w2,
                                                  const float* __restrict__ bias,
                                                  float* __restrict__ out) {
    const int n = blockIdx.x;
    __shared__ float pin[32 * 18 * 20];   // rows padded to 20 floats (16B aligned)
    __shared__ float maxbuf[64 * 49];
    const int tid = threadIdx.x;
    for (int idx = tid; idx < 32 * 360; idx += 256) pin[idx] = 0.f;
    __syncthreads();
    for (int idx = tid; idx < 6272; idx += 256) {
        int ic = idx / 196, r = idx % 196, y = r / 14, x = r % 14;
        pin[ic * 360 + (y + 2) * 20 + (x + 2)] = in[(size_t)n * 6272 + idx];
    }
    __syncthreads();

    const int lane = tid & 63, q = tid >> 6;
    const int oc = lane, dy = q >> 1, dx = q & 1;
    float acc[49];
    {
        float b = bias[oc];
        #pragma unroll
        for (int p = 0; p < 49; ++p) acc[p] = b;
    }
    for (int ic = 0; ic < 32; ++ic) {
        float wk[28];
        const float4* wp = (const float4*)(w2 + ((size_t)ic * 64 + oc) * 28);
        #pragma unroll
        for (int v = 0; v < 7; ++v) {
            float4 t = wp[v];
            wk[4 * v + 0] = t.x; wk[4 * v + 1] = t.y;
            wk[4 * v + 2] = t.z; wk[4 * v + 3] = t.w;
        }
        const float* prow = pin + ic * 360 + dy * 20;
        if (dx == 0) conv_ic<0>(prow, wk, acc);
        else         conv_ic<1>(prow, wk, acc);
    }
    __syncthreads();
    // max across the 4 quadrant-waves, sequentially (cheap: once per image)
    for (int qq = 0; qq < 4; ++qq) {
        if (q == qq) {
            if (qq == 0) {
                #pragma unroll
                for (int p = 0; p < 49; ++p) maxbuf[oc * 49 + p] = acc[p];
            } else {
                #pragma unroll
                for (int p = 0; p < 49; ++p)
                    maxbuf[oc * 49 + p] = fmaxf(maxbuf[oc * 49 + p], acc[p]);
            }
        }
        __syncthreads();
    }
    for (int idx = tid; idx < 3136; idx += 256)
        out[(size_t)n * 3136 + idx] = fmaxf(maxbuf[idx], 0.f);
}

// ---------------- fc1 GEMM: [1152,3136] @ [512,3136]^T + b ----------------
// rows < 1024 -> lat ; rows >= 1024 -> rep = tanh(...)
__global__ __launch_bounds__(256) void fc1_gemm(const float* __restrict__ A,
                                                const float* __restrict__ B,
                                                const float* __restrict__ bias,
                                                float* __restrict__ lat,
                                                float* __restrict__ rep) {
    __shared__ float As[16][68];
    __shared__ float Bs[16][68];
    const int tid = threadIdx.x;
    const int n0 = blockIdx.x * 64, m0 = blockIdx.y * 64;
    const int lr = tid >> 2;           // 0..63
    const int lk = (tid & 3) * 4;      // 0,4,8,12
    const int ty = tid >> 4, tx = tid & 15;
    float c[4][4] = {};
    for (int k0 = 0; k0 < 3136; k0 += 16) {
        float4 a4 = *(const float4*)(A + (size_t)(n0 + lr) * 3136 + k0 + lk);
        float4 b4 = *(const float4*)(B + (size_t)(m0 + lr) * 3136 + k0 + lk);
        __syncthreads();
        As[lk + 0][lr] = a4.x; As[lk + 1][lr] = a4.y; As[lk + 2][lr] = a4.z; As[lk + 3][lr] = a4.w;
        Bs[lk + 0][lr] = b4.x; Bs[lk + 1][lr] = b4.y; Bs[lk + 2][lr] = b4.z; Bs[lk + 3][lr] = b4.w;
        __syncthreads();
        #pragma unroll
        for (int kk = 0; kk < 16; ++kk) {
            float av[4], bv[4];
            #pragma unroll
            for (int i = 0; i < 4; ++i) av[i] = As[kk][ty * 4 + i];
            #pragma unroll
            for (int j = 0; j < 4; ++j) bv[j] = Bs[kk][tx * 4 + j];
            #pragma unroll
            for (int i = 0; i < 4; ++i)
            #pragma unroll
            for (int j = 0; j < 4; ++j) c[i][j] += av[i] * bv[j];
        }
    }
    #pragma unroll
    for (int i = 0; i < 4; ++i)
    #pragma unroll
    for (int j = 0; j < 4; ++j) {
        int n = n0 + ty * 4 + i, m = m0 + tx * 4 + j;
        float v = c[i][j] + bias[m];
        if (n < 1024) lat[n * 512 + m] = v;
        else rep[(n - 1024) * 512 + m] = tanhf(v);
    }
}

// ---------------- label = softmax(lat @ fcn_w.T + fcn_b) ----------------
__global__ __launch_bounds__(128) void fcn_softmax(const float* __restrict__ lat,
                                                   const float* __restrict__ fw,
                                                   const float* __restrict__ fb,
                                                   float* __restrict__ out) {
    const int b = blockIdx.x;
    const int j = threadIdx.x;   // 0..127
    __shared__ float lrow[512];
    __shared__ float red[128];
    for (int i = j; i < 512; i += 128) lrow[i] = lat[b * 512 + i];
    __syncthreads();
    const float4* w4 = (const float4*)(fw + j * 512);
    float acc = fb[j];
    #pragma unroll 4
    for (int q = 0; q < 128; ++q) {
        float4 a = ((const float4*)lrow)[q];
        float4 w = w4[q];
        acc += a.x * w.x + a.y * w.y + a.z * w.z + a.w * w.w;
    }
    red[j] = acc;
    __syncthreads();
    for (int off = 64; off >= 1; off >>= 1) {
        if (j < off) red[j] = fmaxf(red[j], red[j + off]);
        __syncthreads();
    }
    float mx = red[0];
    __syncthreads();
    float ex = expf(acc - mx);
    red[j] = ex;
    __syncthreads();
    for (int off = 64; off >= 1; off >>= 1) {
        if (j < off) red[j] += red[j + off];
        __syncthreads();
    }
    out[b * 128 + j] = ex / red[0];
}

// ---------------- rho = mean(rep) ----------------
__global__ __launch_bounds__(256) void rho_kernel(const float* __restrict__ rep,
                                                  float* __restrict__ rho) {
    __shared__ float red[256];
    const int tid = threadIdx.x;
    float s = 0.f;
    for (int i = tid; i < LABEL * LATENT; i += 256) s += rep[i];
    red[tid] = s;
    __syncthreads();
    for (int off = 128; off >= 1; off >>= 1) {
        if (tid < off) red[tid] += red[tid + off];
        __syncthreads();
    }
    if (tid == 0) rho[0] = red[0] / (float)(LABEL * LATENT);
}

// ---------------- tT[i][k] = rep[k][i] - rho ----------------
__global__ __launch_bounds__(256) void t_kernel(const float* __restrict__ rep,
                                                const float* __restrict__ rho,
                                                float* __restrict__ tT) {
    int idx = blockIdx.x * 256 + threadIdx.x;   // 65536 total
    int i = idx / 128, k = idx % 128;
    tT[idx] = rep[k * 512 + i] - rho[0];
}

// ---------------- w[i][j] = dot(tT_i, tT_j)/128, zero diag ----------------
__global__ __launch_bounds__(256) void w_kernel(const float* __restrict__ tT,
                                                float* __restrict__ w) {
    int idx = blockIdx.x * 256 + threadIdx.x;   // 262144 total
    int i = idx >> 9, j = idx & 511;
    const float4* a = (const float4*)(tT + i * 128);
    const float4* b = (const float4*)(tT + j * 128);
    float acc = 0.f;
    #pragma unroll 8
    for (int q = 0; q < 32; ++q) {
        float4 av = a[q], bv = b[q];
        acc += av.x * bv.x + av.y * bv.y + av.z * bv.z + av.w * bv.w;
    }
    w[idx] = (i == j) ? 0.f : acc * (1.f / 128.f);
}

// ---------------- clustering + fused out = softmax(|min_s @ rep.T|) ----------------
// One block handles CB batch rows. 256 threads; thread owns columns 2*tid, 2*tid+1.
// w is exactly symmetric, so the energy matvec of iter k is the update matvec of
// iter k+1 -> one matvec per iteration. Synchronous Hopfield with symmetric W
// has period <= 2 (Goles), so stopping when s_k == s_{k-1} (fixed point) or
// s_k == s_{k-2} (2-cycle) is exactly equivalent to running all 512 iterations.
#define CB 4
__device__ __forceinline__ float sgnf(float x) {
    return (x > 0.f) ? 1.f : ((x < 0.f) ? -1.f : 0.f);
}

__global__ __launch_bounds__(256) void clustering(const float* __restrict__ lat,
                                                  const float* __restrict__ w,
                                                  const float* __restrict__ rep,
                                                  float* __restrict__ out) {
    const int tid = threadIdx.x;
    const int row0 = blockIdx.x * CB;
    __shared__ float buf[3][CB][512];
    __shared__ float mins[CB][512];
    __shared__ float red[256];
    __shared__ float part_e[4][CB];
    __shared__ int part_f[4];
    __shared__ float min_e[CB];
    __shared__ int copyf[CB];
    __shared__ int donef[CB];
    const int i0 = 2 * tid, i1 = 2 * tid + 1;
    const int wave = tid >> 6, lane = tid & 63;

    #pragma unroll
    for (int r = 0; r < CB; ++r) {
        buf[0][r][i0] = tanhf(lat[(row0 + r) * 512 + i0]);
        buf[0][r][i1] = tanhf(lat[(row0 + r) * 512 + i1]);
    }
    if (tid < CB) { min_e[tid] = INFINITY; donef[tid] = 0; }
    __syncthreads();

    // h_0 = s_0 @ w
    float h0[CB], h1[CB];
    #pragma unroll
    for (int r = 0; r < CB; ++r) { h0[r] = 0.f; h1[r] = 0.f; }
    #pragma unroll 4
    for (int j = 0; j < 512; ++j) {
        float2 wv = *(const float2*)(w + (size_t)j * 512 + i0);
        #pragma unroll
        for (int r = 0; r < CB; ++r) {
            float sj = buf[0][r][j];
            h0[r] += sj * wv.x;
            h1[r] += sj * wv.y;
        }
    }

    for (int k = 1; k <= 512; ++k) {
        const int nw = k % 3, pv = (k + 2) % 3, pp = (k + 1) % 3;
        float sn0[CB], sn1[CB];
        int eqbits = 0xFF;
        #pragma unroll
        for (int r = 0; r < CB; ++r) {
            float p0 = buf[pv][r][i0], p1 = buf[pv][r][i1];
            float q0 = buf[pp][r][i0], q1 = buf[pp][r][i1];
            sn0[r] = fabsf(p0) * sgnf(h0[r]);
            sn1[r] = fabsf(p1) * sgnf(h1[r]);
            if (!(sn0[r] == p0 && sn1[r] == p1)) eqbits &= ~(1 << r);
            if (!(sn0[r] == q0 && sn1[r] == q1)) eqbits &= ~(1 << (4 + r));
            buf[nw][r][i0] = sn0[r];
            buf[nw][r][i1] = sn1[r];
        }
        __syncthreads();
        // h_k = s_k @ w   (doubles as energy matvec)
        #pragma unroll
        for (int r = 0; r < CB; ++r) { h0[r] = 0.f; h1[r] = 0.f; }
        #pragma unroll 4
        for (int j = 0; j < 512; ++j) {
            float2 wv = *(const float2*)(w + (size_t)j * 512 + i0);
            #pragma unroll
            for (int r = 0; r < CB; ++r) {
                float sj = buf[nw][r][j];
                h0[r] += sj * wv.x;
                h1[r] += sj * wv.y;
            }
        }
        float ep[CB];
        #pragma unroll
        for (int r = 0; r < CB; ++r) ep[r] = sn0[r] * h0[r] + sn1[r] * h1[r];
        // butterfly reduce within wave (sum e, and flags)
        #pragma unroll
        for (int m = 32; m >= 1; m >>= 1) {
            #pragma unroll
            for (int r = 0; r < CB; ++r) ep[r] += __shfl_xor(ep[r], m, 64);
            eqbits &= __shfl_xor(eqbits, m, 64);
        }
        if (lane == 0) {
            #pragma unroll
            for (int r = 0; r < CB; ++r) part_e[wave][r] = ep[r];
            part_f[wave] = eqbits;
        }
        __syncthreads();
        if (tid < CB) {
            int r = tid;
            float e = -(part_e[0][r] + part_e[1][r] + part_e[2][r] + part_e[3][r]);
            int fl = part_f[0] & part_f[1] & part_f[2] & part_f[3];
            int better = e < min_e[r];
            if (better) min_e[r] = e;
            copyf[r] = better;
            int fixedp = (fl >> r) & 1;
            int cyc = (k >= 2) && ((fl >> (4 + r)) & 1);
            if (fixedp || cyc) donef[r] = 1;
        }
        __syncthreads();
        int alldone = 1;
        #pragma unroll
        for (int r = 0; r < CB; ++r) {
            if (copyf[r]) { mins[r][i0] = sn0[r]; mins[r][i1] = sn1[r]; }
            alldone &= donef[r];
        }
        if (alldone) break;
    }
    __syncthreads();

    // out[row] = softmax_j(|sum_i mins[i] * rep[j][i]|)
    const int j = tid & 127, half = tid >> 7;
    for (int r = 0; r < CB; ++r) {
        const float4* rr = (const float4*)(rep + (size_t)j * 512 + half * 256);
        const float4* ms = (const float4*)(&mins[r][half * 256]);
        float p = 0.f;
        #pragma unroll 8
        for (int q = 0; q < 64; ++q) {
            float4 rv = rr[q], mv = ms[q];
            p += rv.x * mv.x + rv.y * mv.y + rv.z * mv.z + rv.w * mv.w;
        }
        red[tid] = p;
        __syncthreads();
        float v = 0.f;
        if (tid < 128) { v = fabsf(red[tid] + red[tid + 128]); red[tid] = v; }
        __syncthreads();
        for (int off = 64; off >= 1; off >>= 1) {
            if (tid < off) red[tid] = fmaxf(red[tid], red[tid + off]);
            __syncthreads();
        }
        float mx = red[0];
        __syncthreads();
        float ex = 0.f;
        if (tid < 128) { ex = expf(v - mx); red[tid] = ex; }
        __syncthreads();
        for (int off = 64; off >= 1; off >>= 1) {
            if (tid < off) red[tid] += red[tid + off];
            __syncthreads();
        }
        if (tid < 128) out[(size_t)(row0 + r) * 128 + tid] = ex / red[0];
        __syncthreads();
    }
}

extern "C" void kernel_launch(void* const* d_in, const int* in_sizes, int n_in,
                              void* d_out, int out_size, void* d_ws, size_t ws_size,
                              hipStream_t stream) {
    const float* image = (const float*)d_in[0];
    const float* limg  = (const float*)d_in[1];
    const float* c1w   = (const float*)d_in[2];
    const float* c1b   = (const float*)d_in[3];
    const float* c2w   = (const float*)d_in[4];
    const float* c2b   = (const float*)d_in[5];
    const float* f1w   = (const float*)d_in[6];
    const float* f1b   = (const float*)d_in[7];
    const float* fnw   = (const float*)d_in[8];
    const float* fnb   = (const float*)d_in[9];
    float* out = (float*)d_out;   // [1024*128 out][1024*128 label]
    float* ws  = (float*)d_ws;

    float* out1 = ws;                          // 1152*6272
    float* out2 = out1 + (size_t)NTOT * 6272;  // 1152*3136
    float* lat  = out2 + (size_t)NTOT * 3136;  // 1024*512
    float* rep  = lat + (size_t)BATCH * 512;   // 128*512
    float* tT   = rep + (size_t)LABEL * 512;   // 512*128
    float* wmat = tT + (size_t)512 * 128;      // 512*512
    float* rho  = wmat + (size_t)512 * 512;    // 1
    float* w2   = rho + 16;                    // 32*64*28 = 57344 (aligned start)

    hipLaunchKernelGGL(w2prep, dim3(224), dim3(256), 0, stream, c2w, w2);
    hipLaunchKernelGGL(conv1_pool, dim3(BATCH), dim3(256), 0, stream, image, c1w, c1b, out1);
    hipLaunchKernelGGL(conv1_pool, dim3(LABEL), dim3(256), 0, stream, limg, c1w, c1b,
                       out1 + (size_t)BATCH * 6272);
    hipLaunchKernelGGL(conv2_pool, dim3(NTOT), dim3(256), 0, stream, out1, w2, c2b, out2);
    hipLaunchKernelGGL(fc1_gemm, dim3(NTOT / 64, 512 / 64), dim3(256), 0, stream,
                       out2, f1w, f1b, lat, rep);
    hipLaunchKernelGGL(fcn_softmax, dim3(BATCH), dim3(128), 0, stream, lat, fnw, fnb,
                       out + (size_t)BATCH * LABEL);
    hipLaunchKernelGGL(rho_kernel, dim3(1), dim3(256), 0, stream, rep, rho);
    hipLaunchKernelGGL(t_kernel, dim3(256), dim3(256), 0, stream, rep, rho, tT);
    hipLaunchKernelGGL(w_kernel, dim3(1024), dim3(256), 0, stream, tT, wmat);
    hipLaunchKernelGGL(clustering, dim3(BATCH / CB), dim3(256), 0, stream, lat, wmat, rep, out);
}